// Round 2
// baseline (4288.491 us; speedup 1.0000x reference)
//
#include <hip/hip_runtime.h>
#include <math.h>

// ============================ constants ============================
constexpr int NPTS = 32768;
constexpr int PPB  = 4;                       // points per block
constexpr int HPAD = 20;                      // padded mv row (floats), 80B (16B aligned)
constexpr long long SOFF = 33554432LL;        // NPTS*64*16, start of scalar outputs

// packed-weight offsets in d_ws (floats)
constexpr int OFF_GBW       = 0;        // [64c][3ch][128r][4]
constexpr int OFF_GBOW      = 98304;    // [64c][3ch][64o][4]
constexpr int OFF_L1W       = 147456;   // [64c][3ch][64o][4]
constexpr int OFF_L2W       = 196608;   // [64c][3ch][64o][4]
constexpr int OFF_GB_S2MV   = 245760;   // [32kq][128r][4]
constexpr int OFF_GBO_S2MV  = 262144;   // [32kq][64o][4]
constexpr int OFF_GBO_MVS2S = 270336;   // [16cq][256o][4]
constexpr int OFF_GBO_S2S   = 286720;   // [32kq][256o][4]
constexpr int OFF_L1_S2MV   = 319488;   // [64kq][64o][4]
constexpr int OFF_L1_MVS2S  = 335872;   // [16cq][256o][4]
constexpr int OFF_L1_S2S    = 352256;   // [64kq][256o][4]
constexpr int OFF_L2_S2MV   = 417792;   // [64kq][64o][4]
constexpr int OFF_L2_MVS2S  = 434176;   // [16cq][128o][4]
constexpr int OFF_L2_S2S    = 442368;   // [64kq][128o][4]
constexpr int W_TOTAL       = 475136;   // floats (~1.9MB)

// ==================== compile-time GA tables ====================
namespace ga {
constexpr int MASK_OF[16] = {0,1,2,4,8,3,5,9,6,10,12,7,11,13,14,15};
constexpr int idx_of_mask(int m){ int r = 0; for(int i=0;i<16;++i) if(MASK_OF[i]==m) r=i; return r; }
constexpr int pcount(int x){ int c=0; while(x){ c += x&1; x >>= 1; } return c; }
constexpr int nswaps(int a,int b){ int s=0; a >>= 1; while(a){ s += pcount(a&b); a >>= 1; } return s; }
constexpr float rsign(int a,int b){ return (nswaps(a,b)&1) ? -1.0f : 1.0f; }
constexpr float dsign(int m){ return rsign(m, 15^m); }
struct Ent { int i, j, k; float s; };
struct GPT { Ent e[192]; };
constexpr GPT make_gp(){
  GPT t{}; int n=0;
  for(int i=0;i<16;++i) for(int j=0;j<16;++j){
    const int a=MASK_OF[i], b=MASK_OF[j];
    if((a & b & 1) != 0) continue;             // e0^2 = 0
    t.e[n].i=i; t.e[n].j=j; t.e[n].k=idx_of_mask(a^b); t.e[n].s=rsign(a,b); ++n;
  }
  return t;
}
struct JNT { Ent e[81]; };
constexpr JNT make_jn(){
  JNT t{}; int n=0;
  for(int i=0;i<16;++i) for(int j=0;j<16;++j){
    const int ci = 15 ^ MASK_OF[i], cj = 15 ^ MASK_OF[j];
    if((ci & cj) != 0) continue;               // duals must be disjoint for wedge
    const int mr = ci ^ cj, mk = 15 ^ mr;
    t.e[n].i=i; t.e[n].j=j; t.e[n].k=idx_of_mask(mk);
    t.e[n].s = dsign(MASK_OF[i]) * dsign(MASK_OF[j]) * rsign(ci,cj) * dsign(mk);
    ++n;
  }
  return t;
}
constexpr GPT GPt = make_gp();
constexpr JNT JNt = make_jn();
} // namespace ga

// ============================ helpers ============================
__device__ __forceinline__ float dot4(float4 a, float4 b){
  return fmaf(a.x,b.x, fmaf(a.y,b.y, fmaf(a.z,b.z, a.w*b.w)));
}
__device__ __forceinline__ float gelu_t(float x){
  const float u = 0.7978845608028654f * x * (1.0f + 0.044715f * x * x);
  return 0.5f * x * (1.0f + tanhf(u));
}
// y[j] += sum over basis maps: w[grade(j)]*x[j] + (e0 blades) w[5+g]*x[partner]
__device__ __forceinline__ void accum_equi(float* __restrict__ a,
                                           const float* __restrict__ w,
                                           const float* __restrict__ x){
  a[0]  = fmaf(w[0],x[0],a[0]);
  a[1]  = fmaf(w[1],x[1],fmaf(w[5],x[0],a[1]));
  a[2]  = fmaf(w[1],x[2],a[2]);
  a[3]  = fmaf(w[1],x[3],a[3]);
  a[4]  = fmaf(w[1],x[4],a[4]);
  a[5]  = fmaf(w[2],x[5],fmaf(w[6],x[2],a[5]));
  a[6]  = fmaf(w[2],x[6],fmaf(w[6],x[3],a[6]));
  a[7]  = fmaf(w[2],x[7],fmaf(w[6],x[4],a[7]));
  a[8]  = fmaf(w[2],x[8],a[8]);
  a[9]  = fmaf(w[2],x[9],a[9]);
  a[10] = fmaf(w[2],x[10],a[10]);
  a[11] = fmaf(w[3],x[11],fmaf(w[7],x[8],a[11]));
  a[12] = fmaf(w[3],x[12],fmaf(w[7],x[9],a[12]));
  a[13] = fmaf(w[3],x[13],fmaf(w[7],x[10],a[13]));
  a[14] = fmaf(w[3],x[14],a[14]);
  a[15] = fmaf(w[4],x[15],fmaf(w[8],x[14],a[15]));
}
__device__ __forceinline__ void ld16(const float* __restrict__ p, float* __restrict__ x){
  const float4 a=*(const float4*)p, b=*(const float4*)(p+4), c=*(const float4*)(p+8), d=*(const float4*)(p+12);
  x[0]=a.x; x[1]=a.y; x[2]=a.z; x[3]=a.w; x[4]=b.x; x[5]=b.y; x[6]=b.z; x[7]=b.w;
  x[8]=c.x; x[9]=c.y; x[10]=c.z; x[11]=c.w; x[12]=d.x; x[13]=d.y; x[14]=d.z; x[15]=d.w;
}
__device__ __forceinline__ void st16(float* __restrict__ p, const float* __restrict__ x){
  *(float4*)(p)    = make_float4(x[0],x[1],x[2],x[3]);
  *(float4*)(p+4)  = make_float4(x[4],x[5],x[6],x[7]);
  *(float4*)(p+8)  = make_float4(x[8],x[9],x[10],x[11]);
  *(float4*)(p+12) = make_float4(x[12],x[13],x[14],x[15]);
}

// ======================= weight repack kernel =======================
__global__ void prep_pack(
    const float* __restrict__ gb_w_mv,   const float* __restrict__ gb_w_s2mv,
    const float* __restrict__ gbo_w_mv,  const float* __restrict__ gbo_w_s2mv,
    const float* __restrict__ gbo_w_mvs2s, const float* __restrict__ gbo_w_s2s,
    const float* __restrict__ l1_w_mv,   const float* __restrict__ l1_w_s2mv,
    const float* __restrict__ l1_w_mvs2s, const float* __restrict__ l1_w_s2s,
    const float* __restrict__ l2_w_mv,   const float* __restrict__ l2_w_s2mv,
    const float* __restrict__ l2_w_mvs2s, const float* __restrict__ l2_w_s2s,
    float* __restrict__ W)
{
  const int idx = blockIdx.x * 256 + threadIdx.x;
  if (idx >= W_TOTAL) return;
  float v = 0.0f;
  if (idx < OFF_GBOW) {                       // gb_w_mv [4,32,64,9] -> [c][ch][128r][4]
    const int l=idx, j=l&3, t=l>>2, r=t&127, t2=t>>7, ch=t2%3, c=t2/3, k=ch*4+j;
    if (k < 9) v = gb_w_mv[(r*64 + c)*9 + k];
  } else if (idx < OFF_L1W) {                 // gbo_w_mv [64,64,9]
    const int l=idx-OFF_GBOW, j=l&3, t=l>>2, o=t&63, t2=t>>6, ch=t2%3, c=t2/3, k=ch*4+j;
    if (k < 9) v = gbo_w_mv[(o*64 + c)*9 + k];
  } else if (idx < OFF_L2W) {                 // l1_w_mv
    const int l=idx-OFF_L1W, j=l&3, t=l>>2, o=t&63, t2=t>>6, ch=t2%3, c=t2/3, k=ch*4+j;
    if (k < 9) v = l1_w_mv[(o*64 + c)*9 + k];
  } else if (idx < OFF_GB_S2MV) {             // l2_w_mv
    const int l=idx-OFF_L2W, j=l&3, t=l>>2, o=t&63, t2=t>>6, ch=t2%3, c=t2/3, k=ch*4+j;
    if (k < 9) v = l2_w_mv[(o*64 + c)*9 + k];
  } else if (idx < OFF_GBO_S2MV) {            // gb_w_s2mv [128r][128k] -> [kq][128r][4]
    const int l=idx-OFF_GB_S2MV, j=l&3, t=l>>2, r=t&127, kq=t>>7;
    v = gb_w_s2mv[r*128 + kq*4 + j];
  } else if (idx < OFF_GBO_MVS2S) {           // gbo_w_s2mv [64][128]
    const int l=idx-OFF_GBO_S2MV, j=l&3, t=l>>2, o=t&63, kq=t>>6;
    v = gbo_w_s2mv[o*128 + kq*4 + j];
  } else if (idx < OFF_GBO_S2S) {             // gbo_w_mvs2s [256][64]
    const int l=idx-OFF_GBO_MVS2S, j=l&3, t=l>>2, o=t&255, cq=t>>8;
    v = gbo_w_mvs2s[o*64 + cq*4 + j];
  } else if (idx < OFF_L1_S2MV) {             // gbo_w_s2s [256][128]
    const int l=idx-OFF_GBO_S2S, j=l&3, t=l>>2, o=t&255, kq=t>>8;
    v = gbo_w_s2s[o*128 + kq*4 + j];
  } else if (idx < OFF_L1_MVS2S) {            // l1_w_s2mv [64][256]
    const int l=idx-OFF_L1_S2MV, j=l&3, t=l>>2, o=t&63, kq=t>>6;
    v = l1_w_s2mv[o*256 + kq*4 + j];
  } else if (idx < OFF_L1_S2S) {              // l1_w_mvs2s [256][64]
    const int l=idx-OFF_L1_MVS2S, j=l&3, t=l>>2, o=t&255, cq=t>>8;
    v = l1_w_mvs2s[o*64 + cq*4 + j];
  } else if (idx < OFF_L2_S2MV) {             // l1_w_s2s [256][256]
    const int l=idx-OFF_L1_S2S, j=l&3, t=l>>2, o=t&255, kq=t>>8;
    v = l1_w_s2s[o*256 + kq*4 + j];
  } else if (idx < OFF_L2_MVS2S) {            // l2_w_s2mv [64][256]
    const int l=idx-OFF_L2_S2MV, j=l&3, t=l>>2, o=t&63, kq=t>>6;
    v = l2_w_s2mv[o*256 + kq*4 + j];
  } else if (idx < OFF_L2_S2S) {              // l2_w_mvs2s [128][64]
    const int l=idx-OFF_L2_MVS2S, j=l&3, t=l>>2, o=t&127, cq=t>>7;
    v = l2_w_mvs2s[o*64 + cq*4 + j];
  } else {                                    // l2_w_s2s [128][256]
    const int l=idx-OFF_L2_S2S, j=l&3, t=l>>2, o=t&127, kq=t>>7;
    v = l2_w_s2s[o*256 + kq*4 + j];
  }
  W[idx] = v;
}

// ========================= fused pipeline =========================
// 4 points/block, 4 waves. Stage A: thread = (row r, point-pair pg), all
// register arrays statically indexed (full unroll) -- NO scratch.
// Stages B/C/D: wave = point, lane = output channel.
__global__ __launch_bounds__(256, 4) void fused(
    const float* __restrict__ xin,   // [N,64,16]
    const float* __restrict__ sinp,  // [N,128]
    const float* __restrict__ gb_b_mv,  const float* __restrict__ gbo_b_mv,
    const float* __restrict__ gbo_b_s,  const float* __restrict__ l1_b_mv,
    const float* __restrict__ l1_b_s,   const float* __restrict__ l2_b_mv,
    const float* __restrict__ l2_b_s,   const float* __restrict__ W,
    float* __restrict__ out)
{
  __shared__ float hid[PPB][64][HPAD];   // 20480 B: mv tile (hidden -> mv1g -> mv2g)
  __shared__ float s1b[PPB][256];        // 4096 B
  __shared__ float s2b[PPB][256];        // 4096 B
  __shared__ float c0b[PPB][64];         // 1024 B: comp-0 snapshot for mvs2s paths

  const int tid  = threadIdx.x;
  const int wv   = tid >> 6;           // wave 0..3
  const int lane = tid & 63;
  const int n0   = blockIdx.x * PPB;

  // ------------------------- Stage A: gb linears + GP/JOIN -------------------------
  {
    const int h  = lane & 31;
    const int pg = lane >> 5;
    const int p0 = pg << 1;            // this thread handles points p0, p0+1
    const int r  = (wv << 5) + h;      // row 0..127 (wave0=left, 1=right, 2=lj, 3=rj)
    float acc[2][16];
    #pragma unroll
    for(int i=0;i<2;++i){
      #pragma unroll
      for(int j=0;j<16;++j) acc[i][j]=0.0f;
    }
    const float* Wg = W + OFF_GBW;
    for(int c=0;c<64;++c){
      const float4 wa = *(const float4*)(Wg + (((c*3+0)<<7) + r)*4);
      const float4 wb = *(const float4*)(Wg + (((c*3+1)<<7) + r)*4);
      const float4 wc = *(const float4*)(Wg + (((c*3+2)<<7) + r)*4);
      const float w12[12] = {wa.x,wa.y,wa.z,wa.w, wb.x,wb.y,wb.z,wb.w, wc.x,wc.y,wc.z,wc.w};
      #pragma unroll
      for(int i=0;i<2;++i){
        float xv[16];
        ld16(xin + ((size_t)(n0+p0+i)*64 + c)*16, xv);
        accum_equi(acc[i], w12, xv);
      }
    }
    { // scalars -> comp0 + bias
      const float bias = gb_b_mv[r];
      const float* Ws = W + OFF_GB_S2MV;
      for(int kq=0;kq<32;++kq){
        const float4 wq = *(const float4*)(Ws + (((kq)<<7) + r)*4);
        #pragma unroll
        for(int i=0;i<2;++i){
          const float4 sv = *(const float4*)(sinp + (size_t)(n0+p0+i)*128 + (kq<<2));
          acc[i][0] += dot4(wq, sv);
        }
      }
      #pragma unroll
      for(int i=0;i<2;++i) acc[i][0] += bias;
    }
    // waves 0 (left) and 2 (lj) stage into LDS; waves 1 (right), 3 (rj) keep registers
    if((wv & 1) == 0){
      const int ch = h + ((wv == 2) ? 32 : 0);
      #pragma unroll
      for(int i=0;i<2;++i) st16(&hid[p0+i][ch][0], acc[i]);
    }
    __syncthreads();
    if(wv == 1){ // geometric product: hid[p][h] = GP(left, right)  [FULL unroll: static idx]
      #pragma unroll
      for(int i=0;i<2;++i){
        const int p = p0 + i;
        float L[16], o16[16];
        ld16(&hid[p][h][0], L);
        #pragma unroll
        for(int j=0;j<16;++j) o16[j]=0.0f;
        #pragma unroll
        for(int n=0;n<192;++n){
          o16[ga::GPt.e[n].k] = fmaf(ga::GPt.e[n].s * L[ga::GPt.e[n].i], acc[i][ga::GPt.e[n].j], o16[ga::GPt.e[n].k]);
        }
        st16(&hid[p][h][0], o16);
        c0b[p][h] = o16[0];
      }
    } else if(wv == 3){ // join: hid[p][32+h] = JOIN(lj, rj) (ref_pss = 1)
      #pragma unroll
      for(int i=0;i<2;++i){
        const int p = p0 + i;
        float L[16], o16[16];
        ld16(&hid[p][32+h][0], L);
        #pragma unroll
        for(int j=0;j<16;++j) o16[j]=0.0f;
        #pragma unroll
        for(int n=0;n<81;++n){
          o16[ga::JNt.e[n].k] = fmaf(ga::JNt.e[n].s * L[ga::JNt.e[n].i], acc[i][ga::JNt.e[n].j], o16[ga::JNt.e[n].k]);
        }
        st16(&hid[p][32+h][0], o16);
        c0b[p][32+h] = o16[0];
      }
    }
    __syncthreads();
  }

  const int o = lane;
  const int p = wv;                    // wave handles one point in stages B/C/D
  const int n = n0 + p;

  // ------------------------- Stage B: gbo linear + norms + gated gelu -------------------------
  float mvg[16];
  {
    float acc[16];
    #pragma unroll
    for(int j=0;j<16;++j) acc[j]=0.0f;
    const float* Wg = W + OFF_GBOW;
    for(int c=0;c<64;++c){
      const float4 wa = *(const float4*)(Wg + (((c*3+0)<<6) + o)*4);
      const float4 wb = *(const float4*)(Wg + (((c*3+1)<<6) + o)*4);
      const float4 wc = *(const float4*)(Wg + (((c*3+2)<<6) + o)*4);
      const float w12[12] = {wa.x,wa.y,wa.z,wa.w, wb.x,wb.y,wb.z,wb.w, wc.x,wc.y,wc.z,wc.w};
      float xv[16];
      ld16(&hid[p][c][0], xv);
      accum_equi(acc, w12, xv);
    }
    float sacc[4] = {0.f,0.f,0.f,0.f};
    for(int kq=0;kq<32;++kq){
      const float4 sv = *(const float4*)(sinp + (size_t)n*128 + (kq<<2));
      const float4 wm = *(const float4*)(W + OFF_GBO_S2MV + (((kq<<6) + o)<<2));
      acc[0] += dot4(wm, sv);
      #pragma unroll
      for(int rr=0;rr<4;++rr){
        const float4 ws = *(const float4*)(W + OFF_GBO_S2S + (((kq<<8) + (rr<<6) + o)<<2));
        sacc[rr] += dot4(ws, sv);
      }
    }
    for(int cq=0;cq<16;++cq){
      const float4 h0 = *(const float4*)(&c0b[p][cq<<2]);
      #pragma unroll
      for(int rr=0;rr<4;++rr){
        const float4 wq = *(const float4*)(W + OFF_GBO_MVS2S + (((cq<<8) + (rr<<6) + o)<<2));
        sacc[rr] += dot4(wq, h0);
      }
    }
    acc[0] += gbo_b_mv[o];
    #pragma unroll
    for(int rr=0;rr<4;++rr) sacc[rr] += gbo_b_s[(rr<<6)+o];

    // equi layer norm (inner product over non-e0 blades, mean over 64 channels)
    float sq = acc[0]*acc[0]+acc[2]*acc[2]+acc[3]*acc[3]+acc[4]*acc[4]
             + acc[8]*acc[8]+acc[9]*acc[9]+acc[10]*acc[10]+acc[14]*acc[14];
    #pragma unroll
    for(int m=1;m<64;m<<=1) sq += __shfl_xor(sq, m);
    const float rs = 1.0f / sqrtf(fmaxf(sq * (1.0f/64.0f), 0.01f));
    #pragma unroll
    for(int j=0;j<16;++j) acc[j] *= rs;
    const float gate = gelu_t(acc[0]);
    #pragma unroll
    for(int j=0;j<16;++j) mvg[j] = gate * acc[j];

    // scalar layer norm (256) + gelu
    float sum = sacc[0]+sacc[1]+sacc[2]+sacc[3];
    float ssq = sacc[0]*sacc[0]+sacc[1]*sacc[1]+sacc[2]*sacc[2]+sacc[3]*sacc[3];
    #pragma unroll
    for(int m=1;m<64;m<<=1){ sum += __shfl_xor(sum, m); ssq += __shfl_xor(ssq, m); }
    const float mu   = sum * (1.0f/256.0f);
    const float var  = ssq * (1.0f/256.0f) - mu*mu;
    const float rstd = rsqrtf(var + 1e-5f);
    #pragma unroll
    for(int rr=0;rr<4;++rr) s1b[p][(rr<<6)+o] = gelu_t((sacc[rr]-mu)*rstd);
  }
  __syncthreads();
  st16(&hid[p][o][0], mvg);
  c0b[p][o] = mvg[0];
  __syncthreads();

  // ------------------------- Stage C: l1 linear + norms + gated gelu -------------------------
  float mv2[16];
  {
    float acc[16];
    #pragma unroll
    for(int j=0;j<16;++j) acc[j]=0.0f;
    const float* Wg = W + OFF_L1W;
    for(int c=0;c<64;++c){
      const float4 wa = *(const float4*)(Wg + (((c*3+0)<<6) + o)*4);
      const float4 wb = *(const float4*)(Wg + (((c*3+1)<<6) + o)*4);
      const float4 wc = *(const float4*)(Wg + (((c*3+2)<<6) + o)*4);
      const float w12[12] = {wa.x,wa.y,wa.z,wa.w, wb.x,wb.y,wb.z,wb.w, wc.x,wc.y,wc.z,wc.w};
      float xv[16];
      ld16(&hid[p][c][0], xv);
      accum_equi(acc, w12, xv);
    }
    float sacc[4] = {0.f,0.f,0.f,0.f};
    for(int kq=0;kq<64;++kq){
      const float4 sv = *(const float4*)(&s1b[p][kq<<2]);
      const float4 wm = *(const float4*)(W + OFF_L1_S2MV + (((kq<<6) + o)<<2));
      acc[0] += dot4(wm, sv);
      #pragma unroll
      for(int rr=0;rr<4;++rr){
        const float4 ws = *(const float4*)(W + OFF_L1_S2S + (((kq<<8) + (rr<<6) + o)<<2));
        sacc[rr] += dot4(ws, sv);
      }
    }
    for(int cq=0;cq<16;++cq){
      const float4 h0 = *(const float4*)(&c0b[p][cq<<2]);
      #pragma unroll
      for(int rr=0;rr<4;++rr){
        const float4 wq = *(const float4*)(W + OFF_L1_MVS2S + (((cq<<8) + (rr<<6) + o)<<2));
        sacc[rr] += dot4(wq, h0);
      }
    }
    acc[0] += l1_b_mv[o];
    #pragma unroll
    for(int rr=0;rr<4;++rr) sacc[rr] += l1_b_s[(rr<<6)+o];

    float sq = acc[0]*acc[0]+acc[2]*acc[2]+acc[3]*acc[3]+acc[4]*acc[4]
             + acc[8]*acc[8]+acc[9]*acc[9]+acc[10]*acc[10]+acc[14]*acc[14];
    #pragma unroll
    for(int m=1;m<64;m<<=1) sq += __shfl_xor(sq, m);
    const float rs = 1.0f / sqrtf(fmaxf(sq * (1.0f/64.0f), 0.01f));
    #pragma unroll
    for(int j=0;j<16;++j) acc[j] *= rs;
    const float gate = gelu_t(acc[0]);
    #pragma unroll
    for(int j=0;j<16;++j) mv2[j] = gate * acc[j];

    float sum = sacc[0]+sacc[1]+sacc[2]+sacc[3];
    float ssq = sacc[0]*sacc[0]+sacc[1]*sacc[1]+sacc[2]*sacc[2]+sacc[3]*sacc[3];
    #pragma unroll
    for(int m=1;m<64;m<<=1){ sum += __shfl_xor(sum, m); ssq += __shfl_xor(ssq, m); }
    const float mu   = sum * (1.0f/256.0f);
    const float var  = ssq * (1.0f/256.0f) - mu*mu;
    const float rstd = rsqrtf(var + 1e-5f);
    #pragma unroll
    for(int rr=0;rr<4;++rr) s2b[p][(rr<<6)+o] = gelu_t((sacc[rr]-mu)*rstd);
  }
  __syncthreads();
  st16(&hid[p][o][0], mv2);
  c0b[p][o] = mv2[0];
  __syncthreads();

  // ------------------------- Stage D: l2 linear (plain) -> global -------------------------
  {
    float acc[16];
    #pragma unroll
    for(int j=0;j<16;++j) acc[j]=0.0f;
    const float* Wg = W + OFF_L2W;
    for(int c=0;c<64;++c){
      const float4 wa = *(const float4*)(Wg + (((c*3+0)<<6) + o)*4);
      const float4 wb = *(const float4*)(Wg + (((c*3+1)<<6) + o)*4);
      const float4 wc = *(const float4*)(Wg + (((c*3+2)<<6) + o)*4);
      const float w12[12] = {wa.x,wa.y,wa.z,wa.w, wb.x,wb.y,wb.z,wb.w, wc.x,wc.y,wc.z,wc.w};
      float xv[16];
      ld16(&hid[p][c][0], xv);
      accum_equi(acc, w12, xv);
    }
    float sacc[2] = {0.f,0.f};
    for(int kq=0;kq<64;++kq){
      const float4 sv = *(const float4*)(&s2b[p][kq<<2]);
      const float4 wm = *(const float4*)(W + OFF_L2_S2MV + (((kq<<6) + o)<<2));
      acc[0] += dot4(wm, sv);
      #pragma unroll
      for(int rr=0;rr<2;++rr){
        const float4 ws = *(const float4*)(W + OFF_L2_S2S + (((kq<<7) + (rr<<6) + o)<<2));
        sacc[rr] += dot4(ws, sv);
      }
    }
    for(int cq=0;cq<16;++cq){
      const float4 h0 = *(const float4*)(&c0b[p][cq<<2]);
      #pragma unroll
      for(int rr=0;rr<2;++rr){
        const float4 wq = *(const float4*)(W + OFF_L2_MVS2S + (((cq<<7) + (rr<<6) + o)<<2));
        sacc[rr] += dot4(wq, h0);
      }
    }
    acc[0] += l2_b_mv[o];
    st16(out + ((size_t)n*64 + o)*16, acc);
    #pragma unroll
    for(int rr=0;rr<2;++rr){
      out[SOFF + (size_t)n*128 + (rr<<6) + o] = sacc[rr] + l2_b_s[(rr<<6)+o];
    }
  }
}

// ============================ host launch ============================
extern "C" void kernel_launch(void* const* d_in, const int* in_sizes, int n_in,
                              void* d_out, int out_size, void* d_ws, size_t ws_size,
                              hipStream_t stream) {
  const float* xin          = (const float*)d_in[0];
  const float* sinp         = (const float*)d_in[1];
  const float* gb_w_mv      = (const float*)d_in[2];
  const float* gb_w_s2mv    = (const float*)d_in[3];
  const float* gb_b_mv      = (const float*)d_in[4];
  const float* gbo_w_mv     = (const float*)d_in[5];
  const float* gbo_w_s2mv   = (const float*)d_in[6];
  const float* gbo_b_mv     = (const float*)d_in[7];
  const float* gbo_w_mvs2s  = (const float*)d_in[8];
  const float* gbo_w_s2s    = (const float*)d_in[9];
  const float* gbo_b_s      = (const float*)d_in[10];
  const float* l1_w_mv      = (const float*)d_in[11];
  const float* l1_w_s2mv    = (const float*)d_in[12];
  const float* l1_b_mv      = (const float*)d_in[13];
  const float* l1_w_mvs2s   = (const float*)d_in[14];
  const float* l1_w_s2s     = (const float*)d_in[15];
  const float* l1_b_s       = (const float*)d_in[16];
  const float* l2_w_mv      = (const float*)d_in[17];
  const float* l2_w_s2mv    = (const float*)d_in[18];
  const float* l2_b_mv      = (const float*)d_in[19];
  const float* l2_w_mvs2s   = (const float*)d_in[20];
  const float* l2_w_s2s     = (const float*)d_in[21];
  const float* l2_b_s       = (const float*)d_in[22];
  float* W   = (float*)d_ws;
  float* out = (float*)d_out;

  prep_pack<<<(W_TOTAL + 255) / 256, 256, 0, stream>>>(
      gb_w_mv, gb_w_s2mv, gbo_w_mv, gbo_w_s2mv, gbo_w_mvs2s, gbo_w_s2s,
      l1_w_mv, l1_w_s2mv, l1_w_mvs2s, l1_w_s2s,
      l2_w_mv, l2_w_s2mv, l2_w_mvs2s, l2_w_s2s, W);

  fused<<<NPTS / PPB, 256, 0, stream>>>(
      xin, sinp, gb_b_mv, gbo_b_mv, gbo_b_s, l1_b_mv, l1_b_s, l2_b_mv, l2_b_s, W, out);
}

// Round 3
// 3092.972 us; speedup vs baseline: 1.3865x; 1.3865x over previous
//
#include <hip/hip_runtime.h>
#include <math.h>

// ============================ constants ============================
constexpr int NPTS = 32768;
constexpr int PPB  = 4;                       // points per block
constexpr int HPAD = 20;                      // padded mv row (floats), 80B (16B aligned)
constexpr long long SOFF = 33554432LL;        // NPTS*64*16, start of scalar outputs

// packed-weight offsets in d_ws (floats)
constexpr int OFF_GBW       = 0;        // [64c][3ch][128r][4]
constexpr int OFF_GBOW      = 98304;    // [64c][3ch][64o][4]
constexpr int OFF_L1W       = 147456;   // [64c][3ch][64o][4]
constexpr int OFF_L2W       = 196608;   // [64c][3ch][64o][4]
constexpr int OFF_GB_S2MV   = 245760;   // [32kq][128r][4]
constexpr int OFF_GBO_S2MV  = 262144;   // [32kq][64o][4]
constexpr int OFF_GBO_MVS2S = 270336;   // [16cq][256o][4]
constexpr int OFF_GBO_S2S   = 286720;   // [32kq][256o][4]
constexpr int OFF_L1_S2MV   = 319488;   // [64kq][64o][4]
constexpr int OFF_L1_MVS2S  = 335872;   // [16cq][256o][4]
constexpr int OFF_L1_S2S    = 352256;   // [64kq][256o][4]
constexpr int OFF_L2_S2MV   = 417792;   // [64kq][64o][4]
constexpr int OFF_L2_MVS2S  = 434176;   // [16cq][128o][4]
constexpr int OFF_L2_S2S    = 442368;   // [64kq][128o][4]
constexpr int W_TOTAL       = 475136;   // floats (~1.9MB)

// ==================== compile-time GA tables ====================
namespace ga {
constexpr int MASK_OF[16] = {0,1,2,4,8,3,5,9,6,10,12,7,11,13,14,15};
constexpr int idx_of_mask(int m){ int r = 0; for(int i=0;i<16;++i) if(MASK_OF[i]==m) r=i; return r; }
constexpr int pcount(int x){ int c=0; while(x){ c += x&1; x >>= 1; } return c; }
constexpr int nswaps(int a,int b){ int s=0; a >>= 1; while(a){ s += pcount(a&b); a >>= 1; } return s; }
constexpr float rsign(int a,int b){ return (nswaps(a,b)&1) ? -1.0f : 1.0f; }
constexpr float dsign(int m){ return rsign(m, 15^m); }
struct Ent { int i, j, k; float s; };
struct GPT { Ent e[192]; };
constexpr GPT make_gp(){
  GPT t{}; int n=0;
  for(int i=0;i<16;++i) for(int j=0;j<16;++j){
    const int a=MASK_OF[i], b=MASK_OF[j];
    if((a & b & 1) != 0) continue;             // e0^2 = 0
    t.e[n].i=i; t.e[n].j=j; t.e[n].k=idx_of_mask(a^b); t.e[n].s=rsign(a,b); ++n;
  }
  return t;
}
struct JNT { Ent e[81]; };
constexpr JNT make_jn(){
  JNT t{}; int n=0;
  for(int i=0;i<16;++i) for(int j=0;j<16;++j){
    const int ci = 15 ^ MASK_OF[i], cj = 15 ^ MASK_OF[j];
    if((ci & cj) != 0) continue;               // duals must be disjoint for wedge
    const int mr = ci ^ cj, mk = 15 ^ mr;
    t.e[n].i=i; t.e[n].j=j; t.e[n].k=idx_of_mask(mk);
    t.e[n].s = dsign(MASK_OF[i]) * dsign(MASK_OF[j]) * rsign(ci,cj) * dsign(mk);
    ++n;
  }
  return t;
}
constexpr GPT GPt = make_gp();
constexpr JNT JNt = make_jn();
} // namespace ga

// ============================ helpers ============================
__device__ __forceinline__ float dot4(float4 a, float4 b){
  return fmaf(a.x,b.x, fmaf(a.y,b.y, fmaf(a.z,b.z, a.w*b.w)));
}
__device__ __forceinline__ float gelu_t(float x){
  const float u = 0.7978845608028654f * x * (1.0f + 0.044715f * x * x);
  return 0.5f * x * (1.0f + tanhf(u));
}
// y[j] += sum over basis maps: w[grade(j)]*x[j] + (e0 blades) w[5+g]*x[partner]
__device__ __forceinline__ void accum_equi(float* __restrict__ a,
                                           const float* __restrict__ w,
                                           const float* __restrict__ x){
  a[0]  = fmaf(w[0],x[0],a[0]);
  a[1]  = fmaf(w[1],x[1],fmaf(w[5],x[0],a[1]));
  a[2]  = fmaf(w[1],x[2],a[2]);
  a[3]  = fmaf(w[1],x[3],a[3]);
  a[4]  = fmaf(w[1],x[4],a[4]);
  a[5]  = fmaf(w[2],x[5],fmaf(w[6],x[2],a[5]));
  a[6]  = fmaf(w[2],x[6],fmaf(w[6],x[3],a[6]));
  a[7]  = fmaf(w[2],x[7],fmaf(w[6],x[4],a[7]));
  a[8]  = fmaf(w[2],x[8],a[8]);
  a[9]  = fmaf(w[2],x[9],a[9]);
  a[10] = fmaf(w[2],x[10],a[10]);
  a[11] = fmaf(w[3],x[11],fmaf(w[7],x[8],a[11]));
  a[12] = fmaf(w[3],x[12],fmaf(w[7],x[9],a[12]));
  a[13] = fmaf(w[3],x[13],fmaf(w[7],x[10],a[13]));
  a[14] = fmaf(w[3],x[14],a[14]);
  a[15] = fmaf(w[4],x[15],fmaf(w[8],x[14],a[15]));
}
__device__ __forceinline__ void ld16(const float* __restrict__ p, float* __restrict__ x){
  const float4 a=*(const float4*)p, b=*(const float4*)(p+4), c=*(const float4*)(p+8), d=*(const float4*)(p+12);
  x[0]=a.x; x[1]=a.y; x[2]=a.z; x[3]=a.w; x[4]=b.x; x[5]=b.y; x[6]=b.z; x[7]=b.w;
  x[8]=c.x; x[9]=c.y; x[10]=c.z; x[11]=c.w; x[12]=d.x; x[13]=d.y; x[14]=d.z; x[15]=d.w;
}
__device__ __forceinline__ void st16(float* __restrict__ p, const float* __restrict__ x){
  *(float4*)(p)    = make_float4(x[0],x[1],x[2],x[3]);
  *(float4*)(p+4)  = make_float4(x[4],x[5],x[6],x[7]);
  *(float4*)(p+8)  = make_float4(x[8],x[9],x[10],x[11]);
  *(float4*)(p+12) = make_float4(x[12],x[13],x[14],x[15]);
}

// ======================= weight repack kernel =======================
__global__ void prep_pack(
    const float* __restrict__ gb_w_mv,   const float* __restrict__ gb_w_s2mv,
    const float* __restrict__ gbo_w_mv,  const float* __restrict__ gbo_w_s2mv,
    const float* __restrict__ gbo_w_mvs2s, const float* __restrict__ gbo_w_s2s,
    const float* __restrict__ l1_w_mv,   const float* __restrict__ l1_w_s2mv,
    const float* __restrict__ l1_w_mvs2s, const float* __restrict__ l1_w_s2s,
    const float* __restrict__ l2_w_mv,   const float* __restrict__ l2_w_s2mv,
    const float* __restrict__ l2_w_mvs2s, const float* __restrict__ l2_w_s2s,
    float* __restrict__ W)
{
  const int idx = blockIdx.x * 256 + threadIdx.x;
  if (idx >= W_TOTAL) return;
  float v = 0.0f;
  if (idx < OFF_GBOW) {                       // gb_w_mv [4,32,64,9] -> [c][ch][128r][4]
    const int l=idx, j=l&3, t=l>>2, r=t&127, t2=t>>7, ch=t2%3, c=t2/3, k=ch*4+j;
    if (k < 9) v = gb_w_mv[(r*64 + c)*9 + k];
  } else if (idx < OFF_L1W) {                 // gbo_w_mv [64,64,9]
    const int l=idx-OFF_GBOW, j=l&3, t=l>>2, o=t&63, t2=t>>6, ch=t2%3, c=t2/3, k=ch*4+j;
    if (k < 9) v = gbo_w_mv[(o*64 + c)*9 + k];
  } else if (idx < OFF_L2W) {                 // l1_w_mv
    const int l=idx-OFF_L1W, j=l&3, t=l>>2, o=t&63, t2=t>>6, ch=t2%3, c=t2/3, k=ch*4+j;
    if (k < 9) v = l1_w_mv[(o*64 + c)*9 + k];
  } else if (idx < OFF_GB_S2MV) {             // l2_w_mv
    const int l=idx-OFF_L2W, j=l&3, t=l>>2, o=t&63, t2=t>>6, ch=t2%3, c=t2/3, k=ch*4+j;
    if (k < 9) v = l2_w_mv[(o*64 + c)*9 + k];
  } else if (idx < OFF_GBO_S2MV) {            // gb_w_s2mv [128r][128k] -> [kq][128r][4]
    const int l=idx-OFF_GB_S2MV, j=l&3, t=l>>2, r=t&127, kq=t>>7;
    v = gb_w_s2mv[r*128 + kq*4 + j];
  } else if (idx < OFF_GBO_MVS2S) {           // gbo_w_s2mv [64][128]
    const int l=idx-OFF_GBO_S2MV, j=l&3, t=l>>2, o=t&63, kq=t>>6;
    v = gbo_w_s2mv[o*128 + kq*4 + j];
  } else if (idx < OFF_GBO_S2S) {             // gbo_w_mvs2s [256][64]
    const int l=idx-OFF_GBO_MVS2S, j=l&3, t=l>>2, o=t&255, cq=t>>8;
    v = gbo_w_mvs2s[o*64 + cq*4 + j];
  } else if (idx < OFF_L1_S2MV) {             // gbo_w_s2s [256][128]
    const int l=idx-OFF_GBO_S2S, j=l&3, t=l>>2, o=t&255, kq=t>>8;
    v = gbo_w_s2s[o*128 + kq*4 + j];
  } else if (idx < OFF_L1_MVS2S) {            // l1_w_s2mv [64][256]
    const int l=idx-OFF_L1_S2MV, j=l&3, t=l>>2, o=t&63, kq=t>>6;
    v = l1_w_s2mv[o*256 + kq*4 + j];
  } else if (idx < OFF_L1_S2S) {              // l1_w_mvs2s [256][64]
    const int l=idx-OFF_L1_MVS2S, j=l&3, t=l>>2, o=t&255, cq=t>>8;
    v = l1_w_mvs2s[o*64 + cq*4 + j];
  } else if (idx < OFF_L2_S2MV) {             // l1_w_s2s [256][256]
    const int l=idx-OFF_L1_S2S, j=l&3, t=l>>2, o=t&255, kq=t>>8;
    v = l1_w_s2s[o*256 + kq*4 + j];
  } else if (idx < OFF_L2_MVS2S) {            // l2_w_s2mv [64][256]
    const int l=idx-OFF_L2_S2MV, j=l&3, t=l>>2, o=t&63, kq=t>>6;
    v = l2_w_s2mv[o*256 + kq*4 + j];
  } else if (idx < OFF_L2_S2S) {              // l2_w_mvs2s [128][64]
    const int l=idx-OFF_L2_MVS2S, j=l&3, t=l>>2, o=t&127, cq=t>>7;
    v = l2_w_mvs2s[o*64 + cq*4 + j];
  } else {                                    // l2_w_s2s [128][256]
    const int l=idx-OFF_L2_S2S, j=l&3, t=l>>2, o=t&127, kq=t>>7;
    v = l2_w_s2s[o*256 + kq*4 + j];
  }
  W[idx] = v;
}

// ========================= fused pipeline =========================
// 4 points/block, 4 waves. Stage A: thread = (row r, point-pair pg), all
// register arrays statically indexed (full unroll) -- NO scratch.
// Stages B/C/D: wave = point, lane = output channel.
// launch_bounds(256,2): min 2 waves/EU -> VGPR cap 256. R2's (256,4) made the
// allocator land at 64 VGPR -> capacity spills (WRITE_SIZE 4.65GB). Do NOT
// tighten this without checking VGPR_Count/WRITE_SIZE.
__global__ __launch_bounds__(256, 2) void fused(
    const float* __restrict__ xin,   // [N,64,16]
    const float* __restrict__ sinp,  // [N,128]
    const float* __restrict__ gb_b_mv,  const float* __restrict__ gbo_b_mv,
    const float* __restrict__ gbo_b_s,  const float* __restrict__ l1_b_mv,
    const float* __restrict__ l1_b_s,   const float* __restrict__ l2_b_mv,
    const float* __restrict__ l2_b_s,   const float* __restrict__ W,
    float* __restrict__ out)
{
  __shared__ float hid[PPB][64][HPAD];   // 20480 B: mv tile (hidden -> mv1g -> mv2g)
  __shared__ float s1b[PPB][256];        // 4096 B
  __shared__ float s2b[PPB][256];        // 4096 B
  __shared__ float c0b[PPB][64];         // 1024 B: comp-0 snapshot for mvs2s paths

  const int tid  = threadIdx.x;
  const int wv   = tid >> 6;           // wave 0..3
  const int lane = tid & 63;
  const int n0   = blockIdx.x * PPB;

  // ------------------------- Stage A: gb linears + GP/JOIN -------------------------
  {
    const int h  = lane & 31;
    const int pg = lane >> 5;
    const int p0 = pg << 1;            // this thread handles points p0, p0+1
    const int r  = (wv << 5) + h;      // row 0..127 (wave0=left, 1=right, 2=lj, 3=rj)
    float acc[2][16];
    #pragma unroll
    for(int i=0;i<2;++i){
      #pragma unroll
      for(int j=0;j<16;++j) acc[i][j]=0.0f;
    }
    const float* Wg = W + OFF_GBW;
    for(int c=0;c<64;++c){
      const float4 wa = *(const float4*)(Wg + (((c*3+0)<<7) + r)*4);
      const float4 wb = *(const float4*)(Wg + (((c*3+1)<<7) + r)*4);
      const float4 wc = *(const float4*)(Wg + (((c*3+2)<<7) + r)*4);
      const float w12[12] = {wa.x,wa.y,wa.z,wa.w, wb.x,wb.y,wb.z,wb.w, wc.x,wc.y,wc.z,wc.w};
      #pragma unroll
      for(int i=0;i<2;++i){
        float xv[16];
        ld16(xin + ((size_t)(n0+p0+i)*64 + c)*16, xv);
        accum_equi(acc[i], w12, xv);
      }
    }
    { // scalars -> comp0 + bias
      const float bias = gb_b_mv[r];
      const float* Ws = W + OFF_GB_S2MV;
      for(int kq=0;kq<32;++kq){
        const float4 wq = *(const float4*)(Ws + (((kq)<<7) + r)*4);
        #pragma unroll
        for(int i=0;i<2;++i){
          const float4 sv = *(const float4*)(sinp + (size_t)(n0+p0+i)*128 + (kq<<2));
          acc[i][0] += dot4(wq, sv);
        }
      }
      #pragma unroll
      for(int i=0;i<2;++i) acc[i][0] += bias;
    }
    // waves 0 (left) and 2 (lj) stage into LDS; waves 1 (right), 3 (rj) keep registers
    if((wv & 1) == 0){
      const int ch = h + ((wv == 2) ? 32 : 0);
      #pragma unroll
      for(int i=0;i<2;++i) st16(&hid[p0+i][ch][0], acc[i]);
    }
    __syncthreads();
    if(wv == 1){ // geometric product: hid[p][h] = GP(left, right)  [FULL unroll: static idx]
      #pragma unroll
      for(int i=0;i<2;++i){
        const int p = p0 + i;
        float L[16], o16[16];
        ld16(&hid[p][h][0], L);
        #pragma unroll
        for(int j=0;j<16;++j) o16[j]=0.0f;
        #pragma unroll
        for(int n=0;n<192;++n){
          o16[ga::GPt.e[n].k] = fmaf(ga::GPt.e[n].s * L[ga::GPt.e[n].i], acc[i][ga::GPt.e[n].j], o16[ga::GPt.e[n].k]);
        }
        st16(&hid[p][h][0], o16);
        c0b[p][h] = o16[0];
      }
    } else if(wv == 3){ // join: hid[p][32+h] = JOIN(lj, rj) (ref_pss = 1)
      #pragma unroll
      for(int i=0;i<2;++i){
        const int p = p0 + i;
        float L[16], o16[16];
        ld16(&hid[p][32+h][0], L);
        #pragma unroll
        for(int j=0;j<16;++j) o16[j]=0.0f;
        #pragma unroll
        for(int n=0;n<81;++n){
          o16[ga::JNt.e[n].k] = fmaf(ga::JNt.e[n].s * L[ga::JNt.e[n].i], acc[i][ga::JNt.e[n].j], o16[ga::JNt.e[n].k]);
        }
        st16(&hid[p][32+h][0], o16);
        c0b[p][32+h] = o16[0];
      }
    }
    __syncthreads();
  }

  const int o = lane;
  const int p = wv;                    // wave handles one point in stages B/C/D
  const int n = n0 + p;

  // ------------------------- Stage B: gbo linear + norms + gated gelu -------------------------
  float mvg[16];
  {
    float acc[16];
    #pragma unroll
    for(int j=0;j<16;++j) acc[j]=0.0f;
    const float* Wg = W + OFF_GBOW;
    for(int c=0;c<64;++c){
      const float4 wa = *(const float4*)(Wg + (((c*3+0)<<6) + o)*4);
      const float4 wb = *(const float4*)(Wg + (((c*3+1)<<6) + o)*4);
      const float4 wc = *(const float4*)(Wg + (((c*3+2)<<6) + o)*4);
      const float w12[12] = {wa.x,wa.y,wa.z,wa.w, wb.x,wb.y,wb.z,wb.w, wc.x,wc.y,wc.z,wc.w};
      float xv[16];
      ld16(&hid[p][c][0], xv);
      accum_equi(acc, w12, xv);
    }
    float sacc[4] = {0.f,0.f,0.f,0.f};
    for(int kq=0;kq<32;++kq){
      const float4 sv = *(const float4*)(sinp + (size_t)n*128 + (kq<<2));
      const float4 wm = *(const float4*)(W + OFF_GBO_S2MV + (((kq<<6) + o)<<2));
      acc[0] += dot4(wm, sv);
      #pragma unroll
      for(int rr=0;rr<4;++rr){
        const float4 ws = *(const float4*)(W + OFF_GBO_S2S + (((kq<<8) + (rr<<6) + o)<<2));
        sacc[rr] += dot4(ws, sv);
      }
    }
    for(int cq=0;cq<16;++cq){
      const float4 h0 = *(const float4*)(&c0b[p][cq<<2]);
      #pragma unroll
      for(int rr=0;rr<4;++rr){
        const float4 wq = *(const float4*)(W + OFF_GBO_MVS2S + (((cq<<8) + (rr<<6) + o)<<2));
        sacc[rr] += dot4(wq, h0);
      }
    }
    acc[0] += gbo_b_mv[o];
    #pragma unroll
    for(int rr=0;rr<4;++rr) sacc[rr] += gbo_b_s[(rr<<6)+o];

    // equi layer norm (inner product over non-e0 blades, mean over 64 channels)
    float sq = acc[0]*acc[0]+acc[2]*acc[2]+acc[3]*acc[3]+acc[4]*acc[4]
             + acc[8]*acc[8]+acc[9]*acc[9]+acc[10]*acc[10]+acc[14]*acc[14];
    #pragma unroll
    for(int m=1;m<64;m<<=1) sq += __shfl_xor(sq, m);
    const float rs = 1.0f / sqrtf(fmaxf(sq * (1.0f/64.0f), 0.01f));
    #pragma unroll
    for(int j=0;j<16;++j) acc[j] *= rs;
    const float gate = gelu_t(acc[0]);
    #pragma unroll
    for(int j=0;j<16;++j) mvg[j] = gate * acc[j];

    // scalar layer norm (256) + gelu
    float sum = sacc[0]+sacc[1]+sacc[2]+sacc[3];
    float ssq = sacc[0]*sacc[0]+sacc[1]*sacc[1]+sacc[2]*sacc[2]+sacc[3]*sacc[3];
    #pragma unroll
    for(int m=1;m<64;m<<=1){ sum += __shfl_xor(sum, m); ssq += __shfl_xor(ssq, m); }
    const float mu   = sum * (1.0f/256.0f);
    const float var  = ssq * (1.0f/256.0f) - mu*mu;
    const float rstd = rsqrtf(var + 1e-5f);
    #pragma unroll
    for(int rr=0;rr<4;++rr) s1b[p][(rr<<6)+o] = gelu_t((sacc[rr]-mu)*rstd);
  }
  __syncthreads();
  st16(&hid[p][o][0], mvg);
  c0b[p][o] = mvg[0];
  __syncthreads();

  // ------------------------- Stage C: l1 linear + norms + gated gelu -------------------------
  float mv2[16];
  {
    float acc[16];
    #pragma unroll
    for(int j=0;j<16;++j) acc[j]=0.0f;
    const float* Wg = W + OFF_L1W;
    for(int c=0;c<64;++c){
      const float4 wa = *(const float4*)(Wg + (((c*3+0)<<6) + o)*4);
      const float4 wb = *(const float4*)(Wg + (((c*3+1)<<6) + o)*4);
      const float4 wc = *(const float4*)(Wg + (((c*3+2)<<6) + o)*4);
      const float w12[12] = {wa.x,wa.y,wa.z,wa.w, wb.x,wb.y,wb.z,wb.w, wc.x,wc.y,wc.z,wc.w};
      float xv[16];
      ld16(&hid[p][c][0], xv);
      accum_equi(acc, w12, xv);
    }
    float sacc[4] = {0.f,0.f,0.f,0.f};
    for(int kq=0;kq<64;++kq){
      const float4 sv = *(const float4*)(&s1b[p][kq<<2]);
      const float4 wm = *(const float4*)(W + OFF_L1_S2MV + (((kq<<6) + o)<<2));
      acc[0] += dot4(wm, sv);
      #pragma unroll
      for(int rr=0;rr<4;++rr){
        const float4 ws = *(const float4*)(W + OFF_L1_S2S + (((kq<<8) + (rr<<6) + o)<<2));
        sacc[rr] += dot4(ws, sv);
      }
    }
    for(int cq=0;cq<16;++cq){
      const float4 h0 = *(const float4*)(&c0b[p][cq<<2]);
      #pragma unroll
      for(int rr=0;rr<4;++rr){
        const float4 wq = *(const float4*)(W + OFF_L1_MVS2S + (((cq<<8) + (rr<<6) + o)<<2));
        sacc[rr] += dot4(wq, h0);
      }
    }
    acc[0] += l1_b_mv[o];
    #pragma unroll
    for(int rr=0;rr<4;++rr) sacc[rr] += l1_b_s[(rr<<6)+o];

    float sq = acc[0]*acc[0]+acc[2]*acc[2]+acc[3]*acc[3]+acc[4]*acc[4]
             + acc[8]*acc[8]+acc[9]*acc[9]+acc[10]*acc[10]+acc[14]*acc[14];
    #pragma unroll
    for(int m=1;m<64;m<<=1) sq += __shfl_xor(sq, m);
    const float rs = 1.0f / sqrtf(fmaxf(sq * (1.0f/64.0f), 0.01f));
    #pragma unroll
    for(int j=0;j<16;++j) acc[j] *= rs;
    const float gate = gelu_t(acc[0]);
    #pragma unroll
    for(int j=0;j<16;++j) mv2[j] = gate * acc[j];

    float sum = sacc[0]+sacc[1]+sacc[2]+sacc[3];
    float ssq = sacc[0]*sacc[0]+sacc[1]*sacc[1]+sacc[2]*sacc[2]+sacc[3]*sacc[3];
    #pragma unroll
    for(int m=1;m<64;m<<=1){ sum += __shfl_xor(sum, m); ssq += __shfl_xor(ssq, m); }
    const float mu   = sum * (1.0f/256.0f);
    const float var  = ssq * (1.0f/256.0f) - mu*mu;
    const float rstd = rsqrtf(var + 1e-5f);
    #pragma unroll
    for(int rr=0;rr<4;++rr) s2b[p][(rr<<6)+o] = gelu_t((sacc[rr]-mu)*rstd);
  }
  __syncthreads();
  st16(&hid[p][o][0], mv2);
  c0b[p][o] = mv2[0];
  __syncthreads();

  // ------------------------- Stage D: l2 linear (plain) -> global -------------------------
  {
    float acc[16];
    #pragma unroll
    for(int j=0;j<16;++j) acc[j]=0.0f;
    const float* Wg = W + OFF_L2W;
    for(int c=0;c<64;++c){
      const float4 wa = *(const float4*)(Wg + (((c*3+0)<<6) + o)*4);
      const float4 wb = *(const float4*)(Wg + (((c*3+1)<<6) + o)*4);
      const float4 wc = *(const float4*)(Wg + (((c*3+2)<<6) + o)*4);
      const float w12[12] = {wa.x,wa.y,wa.z,wa.w, wb.x,wb.y,wb.z,wb.w, wc.x,wc.y,wc.z,wc.w};
      float xv[16];
      ld16(&hid[p][c][0], xv);
      accum_equi(acc, w12, xv);
    }
    float sacc[2] = {0.f,0.f};
    for(int kq=0;kq<64;++kq){
      const float4 sv = *(const float4*)(&s2b[p][kq<<2]);
      const float4 wm = *(const float4*)(W + OFF_L2_S2MV + (((kq<<6) + o)<<2));
      acc[0] += dot4(wm, sv);
      #pragma unroll
      for(int rr=0;rr<2;++rr){
        const float4 ws = *(const float4*)(W + OFF_L2_S2S + (((kq<<7) + (rr<<6) + o)<<2));
        sacc[rr] += dot4(ws, sv);
      }
    }
    for(int cq=0;cq<16;++cq){
      const float4 h0 = *(const float4*)(&c0b[p][cq<<2]);
      #pragma unroll
      for(int rr=0;rr<2;++rr){
        const float4 wq = *(const float4*)(W + OFF_L2_MVS2S + (((cq<<7) + (rr<<6) + o)<<2));
        sacc[rr] += dot4(wq, h0);
      }
    }
    acc[0] += l2_b_mv[o];
    st16(out + ((size_t)n*64 + o)*16, acc);
    #pragma unroll
    for(int rr=0;rr<2;++rr){
      out[SOFF + (size_t)n*128 + (rr<<6) + o] = sacc[rr] + l2_b_s[(rr<<6)+o];
    }
  }
}

// ============================ host launch ============================
extern "C" void kernel_launch(void* const* d_in, const int* in_sizes, int n_in,
                              void* d_out, int out_size, void* d_ws, size_t ws_size,
                              hipStream_t stream) {
  const float* xin          = (const float*)d_in[0];
  const float* sinp         = (const float*)d_in[1];
  const float* gb_w_mv      = (const float*)d_in[2];
  const float* gb_w_s2mv    = (const float*)d_in[3];
  const float* gb_b_mv      = (const float*)d_in[4];
  const float* gbo_w_mv     = (const float*)d_in[5];
  const float* gbo_w_s2mv   = (const float*)d_in[6];
  const float* gbo_b_mv     = (const float*)d_in[7];
  const float* gbo_w_mvs2s  = (const float*)d_in[8];
  const float* gbo_w_s2s    = (const float*)d_in[9];
  const float* gbo_b_s      = (const float*)d_in[10];
  const float* l1_w_mv      = (const float*)d_in[11];
  const float* l1_w_s2mv    = (const float*)d_in[12];
  const float* l1_b_mv      = (const float*)d_in[13];
  const float* l1_w_mvs2s   = (const float*)d_in[14];
  const float* l1_w_s2s     = (const float*)d_in[15];
  const float* l1_b_s       = (const float*)d_in[16];
  const float* l2_w_mv      = (const float*)d_in[17];
  const float* l2_w_s2mv    = (const float*)d_in[18];
  const float* l2_b_mv      = (const float*)d_in[19];
  const float* l2_w_mvs2s   = (const float*)d_in[20];
  const float* l2_w_s2s     = (const float*)d_in[21];
  const float* l2_b_s       = (const float*)d_in[22];
  float* W   = (float*)d_ws;
  float* out = (float*)d_out;

  prep_pack<<<(W_TOTAL + 255) / 256, 256, 0, stream>>>(
      gb_w_mv, gb_w_s2mv, gbo_w_mv, gbo_w_s2mv, gbo_w_mvs2s, gbo_w_s2s,
      l1_w_mv, l1_w_s2mv, l1_w_mvs2s, l1_w_s2s,
      l2_w_mv, l2_w_s2mv, l2_w_mvs2s, l2_w_s2s, W);

  fused<<<NPTS / PPB, 256, 0, stream>>>(
      xin, sinp, gb_b_mv, gbo_b_mv, gbo_b_s, l1_b_mv, l1_b_s, l2_b_mv, l2_b_s, W, out);
}

// Round 4
// 2798.948 us; speedup vs baseline: 1.5322x; 1.1050x over previous
//
#include <hip/hip_runtime.h>
#include <math.h>

// ============================ constants ============================
constexpr int NPTS = 32768;
constexpr int PPB  = 4;                       // points per block
constexpr int HPAD = 20;                      // padded mv row (floats), 80B (16B aligned)
constexpr long long SOFF = 33554432LL;        // NPTS*64*16, start of scalar outputs

// packed-weight offsets in d_ws (floats)
constexpr int OFF_GBW       = 0;        // [64c][3ch][128r][4]
constexpr int OFF_GBOW      = 98304;    // [64c][3ch][64o][4]
constexpr int OFF_L1W       = 147456;   // [64c][3ch][64o][4]
constexpr int OFF_L2W       = 196608;   // [64c][3ch][64o][4]
constexpr int OFF_GB_S2MV   = 245760;   // [32kq][128r][4]
constexpr int OFF_GBO_S2MV  = 262144;   // [32kq][64o][4]
constexpr int OFF_GBO_MVS2S = 270336;   // [16cq][256o][4]
constexpr int OFF_GBO_S2S   = 286720;   // [32kq][256o][4]
constexpr int OFF_L1_S2MV   = 319488;   // [64kq][64o][4]
constexpr int OFF_L1_MVS2S  = 335872;   // [16cq][256o][4]
constexpr int OFF_L1_S2S    = 352256;   // [64kq][256o][4]
constexpr int OFF_L2_S2MV   = 417792;   // [64kq][64o][4]
constexpr int OFF_L2_MVS2S  = 434176;   // [16cq][128o][4]
constexpr int OFF_L2_S2S    = 442368;   // [64kq][128o][4]
constexpr int W_TOTAL       = 475136;   // floats (~1.9MB)

// ==================== compile-time GA tables ====================
namespace ga {
constexpr int MASK_OF[16] = {0,1,2,4,8,3,5,9,6,10,12,7,11,13,14,15};
constexpr int idx_of_mask(int m){ int r = 0; for(int i=0;i<16;++i) if(MASK_OF[i]==m) r=i; return r; }
constexpr int pcount(int x){ int c=0; while(x){ c += x&1; x >>= 1; } return c; }
constexpr int nswaps(int a,int b){ int s=0; a >>= 1; while(a){ s += pcount(a&b); a >>= 1; } return s; }
constexpr float rsign(int a,int b){ return (nswaps(a,b)&1) ? -1.0f : 1.0f; }
constexpr float dsign(int m){ return rsign(m, 15^m); }
struct Ent { int i, j, k; float s; };
struct GPT { Ent e[192]; };
constexpr GPT make_gp(){
  GPT t{}; int n=0;
  for(int i=0;i<16;++i) for(int j=0;j<16;++j){
    const int a=MASK_OF[i], b=MASK_OF[j];
    if((a & b & 1) != 0) continue;             // e0^2 = 0
    t.e[n].i=i; t.e[n].j=j; t.e[n].k=idx_of_mask(a^b); t.e[n].s=rsign(a,b); ++n;
  }
  return t;
}
struct JNT { Ent e[81]; };
constexpr JNT make_jn(){
  JNT t{}; int n=0;
  for(int i=0;i<16;++i) for(int j=0;j<16;++j){
    const int ci = 15 ^ MASK_OF[i], cj = 15 ^ MASK_OF[j];
    if((ci & cj) != 0) continue;               // duals must be disjoint for wedge
    const int mr = ci ^ cj, mk = 15 ^ mr;
    t.e[n].i=i; t.e[n].j=j; t.e[n].k=idx_of_mask(mk);
    t.e[n].s = dsign(MASK_OF[i]) * dsign(MASK_OF[j]) * rsign(ci,cj) * dsign(mk);
    ++n;
  }
  return t;
}
constexpr GPT GPt = make_gp();
constexpr JNT JNt = make_jn();
} // namespace ga

// ============================ helpers ============================
__device__ __forceinline__ float dot4(float4 a, float4 b){
  return fmaf(a.x,b.x, fmaf(a.y,b.y, fmaf(a.z,b.z, a.w*b.w)));
}
__device__ __forceinline__ float gelu_t(float x){
  const float u = 0.7978845608028654f * x * (1.0f + 0.044715f * x * x);
  return 0.5f * x * (1.0f + tanhf(u));
}
// y[j] += sum over basis maps: w[grade(j)]*x[j] + (e0 blades) w[5+g]*x[partner]
__device__ __forceinline__ void accum_equi(float* __restrict__ a,
                                           const float* __restrict__ w,
                                           const float* __restrict__ x){
  a[0]  = fmaf(w[0],x[0],a[0]);
  a[1]  = fmaf(w[1],x[1],fmaf(w[5],x[0],a[1]));
  a[2]  = fmaf(w[1],x[2],a[2]);
  a[3]  = fmaf(w[1],x[3],a[3]);
  a[4]  = fmaf(w[1],x[4],a[4]);
  a[5]  = fmaf(w[2],x[5],fmaf(w[6],x[2],a[5]));
  a[6]  = fmaf(w[2],x[6],fmaf(w[6],x[3],a[6]));
  a[7]  = fmaf(w[2],x[7],fmaf(w[6],x[4],a[7]));
  a[8]  = fmaf(w[2],x[8],a[8]);
  a[9]  = fmaf(w[2],x[9],a[9]);
  a[10] = fmaf(w[2],x[10],a[10]);
  a[11] = fmaf(w[3],x[11],fmaf(w[7],x[8],a[11]));
  a[12] = fmaf(w[3],x[12],fmaf(w[7],x[9],a[12]));
  a[13] = fmaf(w[3],x[13],fmaf(w[7],x[10],a[13]));
  a[14] = fmaf(w[3],x[14],a[14]);
  a[15] = fmaf(w[4],x[15],fmaf(w[8],x[14],a[15]));
}
__device__ __forceinline__ void ld16(const float* __restrict__ p, float* __restrict__ x){
  const float4 a=*(const float4*)p, b=*(const float4*)(p+4), c=*(const float4*)(p+8), d=*(const float4*)(p+12);
  x[0]=a.x; x[1]=a.y; x[2]=a.z; x[3]=a.w; x[4]=b.x; x[5]=b.y; x[6]=b.z; x[7]=b.w;
  x[8]=c.x; x[9]=c.y; x[10]=c.z; x[11]=c.w; x[12]=d.x; x[13]=d.y; x[14]=d.z; x[15]=d.w;
}
__device__ __forceinline__ void st16(float* __restrict__ p, const float* __restrict__ x){
  *(float4*)(p)    = make_float4(x[0],x[1],x[2],x[3]);
  *(float4*)(p+4)  = make_float4(x[4],x[5],x[6],x[7]);
  *(float4*)(p+8)  = make_float4(x[8],x[9],x[10],x[11]);
  *(float4*)(p+12) = make_float4(x[12],x[13],x[14],x[15]);
}

// ======================= weight repack kernel =======================
__global__ void prep_pack(
    const float* __restrict__ gb_w_mv,   const float* __restrict__ gb_w_s2mv,
    const float* __restrict__ gbo_w_mv,  const float* __restrict__ gbo_w_s2mv,
    const float* __restrict__ gbo_w_mvs2s, const float* __restrict__ gbo_w_s2s,
    const float* __restrict__ l1_w_mv,   const float* __restrict__ l1_w_s2mv,
    const float* __restrict__ l1_w_mvs2s, const float* __restrict__ l1_w_s2s,
    const float* __restrict__ l2_w_mv,   const float* __restrict__ l2_w_s2mv,
    const float* __restrict__ l2_w_mvs2s, const float* __restrict__ l2_w_s2s,
    float* __restrict__ W)
{
  const int idx = blockIdx.x * 256 + threadIdx.x;
  if (idx >= W_TOTAL) return;
  float v = 0.0f;
  if (idx < OFF_GBOW) {                       // gb_w_mv [4,32,64,9] -> [c][ch][128r][4]
    const int l=idx, j=l&3, t=l>>2, r=t&127, t2=t>>7, ch=t2%3, c=t2/3, k=ch*4+j;
    if (k < 9) v = gb_w_mv[(r*64 + c)*9 + k];
  } else if (idx < OFF_L1W) {                 // gbo_w_mv [64,64,9]
    const int l=idx-OFF_GBOW, j=l&3, t=l>>2, o=t&63, t2=t>>6, ch=t2%3, c=t2/3, k=ch*4+j;
    if (k < 9) v = gbo_w_mv[(o*64 + c)*9 + k];
  } else if (idx < OFF_L2W) {                 // l1_w_mv
    const int l=idx-OFF_L1W, j=l&3, t=l>>2, o=t&63, t2=t>>6, ch=t2%3, c=t2/3, k=ch*4+j;
    if (k < 9) v = l1_w_mv[(o*64 + c)*9 + k];
  } else if (idx < OFF_GB_S2MV) {             // l2_w_mv
    const int l=idx-OFF_L2W, j=l&3, t=l>>2, o=t&63, t2=t>>6, ch=t2%3, c=t2/3, k=ch*4+j;
    if (k < 9) v = l2_w_mv[(o*64 + c)*9 + k];
  } else if (idx < OFF_GBO_S2MV) {            // gb_w_s2mv [128r][128k] -> [kq][128r][4]
    const int l=idx-OFF_GB_S2MV, j=l&3, t=l>>2, r=t&127, kq=t>>7;
    v = gb_w_s2mv[r*128 + kq*4 + j];
  } else if (idx < OFF_GBO_MVS2S) {           // gbo_w_s2mv [64][128]
    const int l=idx-OFF_GBO_S2MV, j=l&3, t=l>>2, o=t&63, kq=t>>6;
    v = gbo_w_s2mv[o*128 + kq*4 + j];
  } else if (idx < OFF_GBO_S2S) {             // gbo_w_mvs2s [256][64]
    const int l=idx-OFF_GBO_MVS2S, j=l&3, t=l>>2, o=t&255, cq=t>>8;
    v = gbo_w_mvs2s[o*64 + cq*4 + j];
  } else if (idx < OFF_L1_S2MV) {             // gbo_w_s2s [256][128]
    const int l=idx-OFF_GBO_S2S, j=l&3, t=l>>2, o=t&255, kq=t>>8;
    v = gbo_w_s2s[o*128 + kq*4 + j];
  } else if (idx < OFF_L1_MVS2S) {            // l1_w_s2mv [64][256]
    const int l=idx-OFF_L1_S2MV, j=l&3, t=l>>2, o=t&63, kq=t>>6;
    v = l1_w_s2mv[o*256 + kq*4 + j];
  } else if (idx < OFF_L1_S2S) {              // l1_w_mvs2s [256][64]
    const int l=idx-OFF_L1_MVS2S, j=l&3, t=l>>2, o=t&255, cq=t>>8;
    v = l1_w_mvs2s[o*64 + cq*4 + j];
  } else if (idx < OFF_L2_S2MV) {             // l1_w_s2s [256][256]
    const int l=idx-OFF_L1_S2S, j=l&3, t=l>>2, o=t&255, kq=t>>8;
    v = l1_w_s2s[o*256 + kq*4 + j];
  } else if (idx < OFF_L2_MVS2S) {            // l2_w_s2mv [64][256]
    const int l=idx-OFF_L2_S2MV, j=l&3, t=l>>2, o=t&63, kq=t>>6;
    v = l2_w_s2mv[o*256 + kq*4 + j];
  } else if (idx < OFF_L2_S2S) {              // l2_w_mvs2s [128][64]
    const int l=idx-OFF_L2_MVS2S, j=l&3, t=l>>2, o=t&127, cq=t>>7;
    v = l2_w_mvs2s[o*64 + cq*4 + j];
  } else {                                    // l2_w_s2s [128][256]
    const int l=idx-OFF_L2_S2S, j=l&3, t=l>>2, o=t&127, kq=t>>7;
    v = l2_w_s2s[o*256 + kq*4 + j];
  }
  W[idx] = v;
}

// ========================= fused pipeline =========================
// 4 points/block, 4 waves. Stage A: thread = (row r, point-pair pg), all
// register arrays statically indexed (full unroll) -- NO dynamic indexing.
// Stages B/C/D: wave = point, lane = output channel.
//
// VGPR-budget law measured on this toolchain (R2/R3): arch-VGPR budget =
// 256 / min_waves_per_EU.  (256,4) -> 64 VGPR (4.65GB spill writes),
// (256,2) -> 128 VGPR (2.5GB spill writes). Kernel demand ~150-200 VGPR,
// so request min_waves=1 -> budget 256 -> no capacity spills.
__global__ __launch_bounds__(256, 1) void fused(
    const float* __restrict__ xin,   // [N,64,16]
    const float* __restrict__ sinp,  // [N,128]
    const float* __restrict__ gb_b_mv,  const float* __restrict__ gbo_b_mv,
    const float* __restrict__ gbo_b_s,  const float* __restrict__ l1_b_mv,
    const float* __restrict__ l1_b_s,   const float* __restrict__ l2_b_mv,
    const float* __restrict__ l2_b_s,   const float* __restrict__ W,
    float* __restrict__ out)
{
  __shared__ float hid[PPB][64][HPAD];   // 20480 B: mv tile (hidden -> mv1g -> mv2g)
  __shared__ float s1b[PPB][256];        // 4096 B
  __shared__ float s2b[PPB][256];        // 4096 B
  __shared__ float c0b[PPB][64];         // 1024 B: comp-0 snapshot for mvs2s paths

  const int tid  = threadIdx.x;
  const int wv   = tid >> 6;           // wave 0..3
  const int lane = tid & 63;
  const int n0   = blockIdx.x * PPB;

  // ------------------------- Stage A: gb linears + GP/JOIN -------------------------
  {
    const int h  = lane & 31;
    const int pg = lane >> 5;
    const int p0 = pg << 1;            // this thread handles points p0, p0+1
    const int r  = (wv << 5) + h;      // row 0..127 (wave0=left, 1=right, 2=lj, 3=rj)
    float acc[2][16];
    #pragma unroll
    for(int i=0;i<2;++i){
      #pragma unroll
      for(int j=0;j<16;++j) acc[i][j]=0.0f;
    }
    const float* Wg = W + OFF_GBW;
    for(int c=0;c<64;++c){
      const float4 wa = *(const float4*)(Wg + (((c*3+0)<<7) + r)*4);
      const float4 wb = *(const float4*)(Wg + (((c*3+1)<<7) + r)*4);
      const float4 wc = *(const float4*)(Wg + (((c*3+2)<<7) + r)*4);
      const float w12[12] = {wa.x,wa.y,wa.z,wa.w, wb.x,wb.y,wb.z,wb.w, wc.x,wc.y,wc.z,wc.w};
      #pragma unroll
      for(int i=0;i<2;++i){
        float xv[16];
        ld16(xin + ((size_t)(n0+p0+i)*64 + c)*16, xv);
        accum_equi(acc[i], w12, xv);
      }
    }
    { // scalars -> comp0 + bias
      const float bias = gb_b_mv[r];
      const float* Ws = W + OFF_GB_S2MV;
      for(int kq=0;kq<32;++kq){
        const float4 wq = *(const float4*)(Ws + (((kq)<<7) + r)*4);
        #pragma unroll
        for(int i=0;i<2;++i){
          const float4 sv = *(const float4*)(sinp + (size_t)(n0+p0+i)*128 + (kq<<2));
          acc[i][0] += dot4(wq, sv);
        }
      }
      #pragma unroll
      for(int i=0;i<2;++i) acc[i][0] += bias;
    }
    // waves 0 (left) and 2 (lj) stage into LDS; waves 1 (right), 3 (rj) keep registers
    if((wv & 1) == 0){
      const int ch = h + ((wv == 2) ? 32 : 0);
      #pragma unroll
      for(int i=0;i<2;++i) st16(&hid[p0+i][ch][0], acc[i]);
    }
    __syncthreads();
    if(wv == 1){ // geometric product: hid[p][h] = GP(left, right)  [FULL unroll: static idx]
      #pragma unroll
      for(int i=0;i<2;++i){
        const int p = p0 + i;
        float L[16], o16[16];
        ld16(&hid[p][h][0], L);
        #pragma unroll
        for(int j=0;j<16;++j) o16[j]=0.0f;
        #pragma unroll
        for(int n=0;n<192;++n){
          o16[ga::GPt.e[n].k] = fmaf(ga::GPt.e[n].s * L[ga::GPt.e[n].i], acc[i][ga::GPt.e[n].j], o16[ga::GPt.e[n].k]);
        }
        st16(&hid[p][h][0], o16);
        c0b[p][h] = o16[0];
      }
    } else if(wv == 3){ // join: hid[p][32+h] = JOIN(lj, rj) (ref_pss = 1)
      #pragma unroll
      for(int i=0;i<2;++i){
        const int p = p0 + i;
        float L[16], o16[16];
        ld16(&hid[p][32+h][0], L);
        #pragma unroll
        for(int j=0;j<16;++j) o16[j]=0.0f;
        #pragma unroll
        for(int n=0;n<81;++n){
          o16[ga::JNt.e[n].k] = fmaf(ga::JNt.e[n].s * L[ga::JNt.e[n].i], acc[i][ga::JNt.e[n].j], o16[ga::JNt.e[n].k]);
        }
        st16(&hid[p][32+h][0], o16);
        c0b[p][32+h] = o16[0];
      }
    }
    __syncthreads();
  }

  const int o = lane;
  const int p = wv;                    // wave handles one point in stages B/C/D
  const int n = n0 + p;

  // ------------------------- Stage B: gbo linear + norms + gated gelu -------------------------
  float mvg[16];
  {
    float acc[16];
    #pragma unroll
    for(int j=0;j<16;++j) acc[j]=0.0f;
    const float* Wg = W + OFF_GBOW;
    for(int c=0;c<64;++c){
      const float4 wa = *(const float4*)(Wg + (((c*3+0)<<6) + o)*4);
      const float4 wb = *(const float4*)(Wg + (((c*3+1)<<6) + o)*4);
      const float4 wc = *(const float4*)(Wg + (((c*3+2)<<6) + o)*4);
      const float w12[12] = {wa.x,wa.y,wa.z,wa.w, wb.x,wb.y,wb.z,wb.w, wc.x,wc.y,wc.z,wc.w};
      float xv[16];
      ld16(&hid[p][c][0], xv);
      accum_equi(acc, w12, xv);
    }
    float sacc[4] = {0.f,0.f,0.f,0.f};
    for(int kq=0;kq<32;++kq){
      const float4 sv = *(const float4*)(sinp + (size_t)n*128 + (kq<<2));
      const float4 wm = *(const float4*)(W + OFF_GBO_S2MV + (((kq<<6) + o)<<2));
      acc[0] += dot4(wm, sv);
      #pragma unroll
      for(int rr=0;rr<4;++rr){
        const float4 ws = *(const float4*)(W + OFF_GBO_S2S + (((kq<<8) + (rr<<6) + o)<<2));
        sacc[rr] += dot4(ws, sv);
      }
    }
    for(int cq=0;cq<16;++cq){
      const float4 h0 = *(const float4*)(&c0b[p][cq<<2]);
      #pragma unroll
      for(int rr=0;rr<4;++rr){
        const float4 wq = *(const float4*)(W + OFF_GBO_MVS2S + (((cq<<8) + (rr<<6) + o)<<2));
        sacc[rr] += dot4(wq, h0);
      }
    }
    acc[0] += gbo_b_mv[o];
    #pragma unroll
    for(int rr=0;rr<4;++rr) sacc[rr] += gbo_b_s[(rr<<6)+o];

    // equi layer norm (inner product over non-e0 blades, mean over 64 channels)
    float sq = acc[0]*acc[0]+acc[2]*acc[2]+acc[3]*acc[3]+acc[4]*acc[4]
             + acc[8]*acc[8]+acc[9]*acc[9]+acc[10]*acc[10]+acc[14]*acc[14];
    #pragma unroll
    for(int m=1;m<64;m<<=1) sq += __shfl_xor(sq, m);
    const float rs = 1.0f / sqrtf(fmaxf(sq * (1.0f/64.0f), 0.01f));
    #pragma unroll
    for(int j=0;j<16;++j) acc[j] *= rs;
    const float gate = gelu_t(acc[0]);
    #pragma unroll
    for(int j=0;j<16;++j) mvg[j] = gate * acc[j];

    // scalar layer norm (256) + gelu
    float sum = sacc[0]+sacc[1]+sacc[2]+sacc[3];
    float ssq = sacc[0]*sacc[0]+sacc[1]*sacc[1]+sacc[2]*sacc[2]+sacc[3]*sacc[3];
    #pragma unroll
    for(int m=1;m<64;m<<=1){ sum += __shfl_xor(sum, m); ssq += __shfl_xor(ssq, m); }
    const float mu   = sum * (1.0f/256.0f);
    const float var  = ssq * (1.0f/256.0f) - mu*mu;
    const float rstd = rsqrtf(var + 1e-5f);
    #pragma unroll
    for(int rr=0;rr<4;++rr) s1b[p][(rr<<6)+o] = gelu_t((sacc[rr]-mu)*rstd);
  }
  __syncthreads();
  st16(&hid[p][o][0], mvg);
  c0b[p][o] = mvg[0];
  __syncthreads();

  // ------------------------- Stage C: l1 linear + norms + gated gelu -------------------------
  float mv2[16];
  {
    float acc[16];
    #pragma unroll
    for(int j=0;j<16;++j) acc[j]=0.0f;
    const float* Wg = W + OFF_L1W;
    for(int c=0;c<64;++c){
      const float4 wa = *(const float4*)(Wg + (((c*3+0)<<6) + o)*4);
      const float4 wb = *(const float4*)(Wg + (((c*3+1)<<6) + o)*4);
      const float4 wc = *(const float4*)(Wg + (((c*3+2)<<6) + o)*4);
      const float w12[12] = {wa.x,wa.y,wa.z,wa.w, wb.x,wb.y,wb.z,wb.w, wc.x,wc.y,wc.z,wc.w};
      float xv[16];
      ld16(&hid[p][c][0], xv);
      accum_equi(acc, w12, xv);
    }
    float sacc[4] = {0.f,0.f,0.f,0.f};
    for(int kq=0;kq<64;++kq){
      const float4 sv = *(const float4*)(&s1b[p][kq<<2]);
      const float4 wm = *(const float4*)(W + OFF_L1_S2MV + (((kq<<6) + o)<<2));
      acc[0] += dot4(wm, sv);
      #pragma unroll
      for(int rr=0;rr<4;++rr){
        const float4 ws = *(const float4*)(W + OFF_L1_S2S + (((kq<<8) + (rr<<6) + o)<<2));
        sacc[rr] += dot4(ws, sv);
      }
    }
    for(int cq=0;cq<16;++cq){
      const float4 h0 = *(const float4*)(&c0b[p][cq<<2]);
      #pragma unroll
      for(int rr=0;rr<4;++rr){
        const float4 wq = *(const float4*)(W + OFF_L1_MVS2S + (((cq<<8) + (rr<<6) + o)<<2));
        sacc[rr] += dot4(wq, h0);
      }
    }
    acc[0] += l1_b_mv[o];
    #pragma unroll
    for(int rr=0;rr<4;++rr) sacc[rr] += l1_b_s[(rr<<6)+o];

    float sq = acc[0]*acc[0]+acc[2]*acc[2]+acc[3]*acc[3]+acc[4]*acc[4]
             + acc[8]*acc[8]+acc[9]*acc[9]+acc[10]*acc[10]+acc[14]*acc[14];
    #pragma unroll
    for(int m=1;m<64;m<<=1) sq += __shfl_xor(sq, m);
    const float rs = 1.0f / sqrtf(fmaxf(sq * (1.0f/64.0f), 0.01f));
    #pragma unroll
    for(int j=0;j<16;++j) acc[j] *= rs;
    const float gate = gelu_t(acc[0]);
    #pragma unroll
    for(int j=0;j<16;++j) mv2[j] = gate * acc[j];

    float sum = sacc[0]+sacc[1]+sacc[2]+sacc[3];
    float ssq = sacc[0]*sacc[0]+sacc[1]*sacc[1]+sacc[2]*sacc[2]+sacc[3]*sacc[3];
    #pragma unroll
    for(int m=1;m<64;m<<=1){ sum += __shfl_xor(sum, m); ssq += __shfl_xor(ssq, m); }
    const float mu   = sum * (1.0f/256.0f);
    const float var  = ssq * (1.0f/256.0f) - mu*mu;
    const float rstd = rsqrtf(var + 1e-5f);
    #pragma unroll
    for(int rr=0;rr<4;++rr) s2b[p][(rr<<6)+o] = gelu_t((sacc[rr]-mu)*rstd);
  }
  __syncthreads();
  st16(&hid[p][o][0], mv2);
  c0b[p][o] = mv2[0];
  __syncthreads();

  // ------------------------- Stage D: l2 linear (plain) -> global -------------------------
  {
    float acc[16];
    #pragma unroll
    for(int j=0;j<16;++j) acc[j]=0.0f;
    const float* Wg = W + OFF_L2W;
    for(int c=0;c<64;++c){
      const float4 wa = *(const float4*)(Wg + (((c*3+0)<<6) + o)*4);
      const float4 wb = *(const float4*)(Wg + (((c*3+1)<<6) + o)*4);
      const float4 wc = *(const float4*)(Wg + (((c*3+2)<<6) + o)*4);
      const float w12[12] = {wa.x,wa.y,wa.z,wa.w, wb.x,wb.y,wb.z,wb.w, wc.x,wc.y,wc.z,wc.w};
      float xv[16];
      ld16(&hid[p][c][0], xv);
      accum_equi(acc, w12, xv);
    }
    float sacc[2] = {0.f,0.f};
    for(int kq=0;kq<64;++kq){
      const float4 sv = *(const float4*)(&s2b[p][kq<<2]);
      const float4 wm = *(const float4*)(W + OFF_L2_S2MV + (((kq<<6) + o)<<2));
      acc[0] += dot4(wm, sv);
      #pragma unroll
      for(int rr=0;rr<2;++rr){
        const float4 ws = *(const float4*)(W + OFF_L2_S2S + (((kq<<7) + (rr<<6) + o)<<2));
        sacc[rr] += dot4(ws, sv);
      }
    }
    for(int cq=0;cq<16;++cq){
      const float4 h0 = *(const float4*)(&c0b[p][cq<<2]);
      #pragma unroll
      for(int rr=0;rr<2;++rr){
        const float4 wq = *(const float4*)(W + OFF_L2_MVS2S + (((cq<<7) + (rr<<6) + o)<<2));
        sacc[rr] += dot4(wq, h0);
      }
    }
    acc[0] += l2_b_mv[o];
    st16(out + ((size_t)n*64 + o)*16, acc);
    #pragma unroll
    for(int rr=0;rr<2;++rr){
      out[SOFF + (size_t)n*128 + (rr<<6) + o] = sacc[rr] + l2_b_s[(rr<<6)+o];
    }
  }
}

// ============================ host launch ============================
extern "C" void kernel_launch(void* const* d_in, const int* in_sizes, int n_in,
                              void* d_out, int out_size, void* d_ws, size_t ws_size,
                              hipStream_t stream) {
  const float* xin          = (const float*)d_in[0];
  const float* sinp         = (const float*)d_in[1];
  const float* gb_w_mv      = (const float*)d_in[2];
  const float* gb_w_s2mv    = (const float*)d_in[3];
  const float* gb_b_mv      = (const float*)d_in[4];
  const float* gbo_w_mv     = (const float*)d_in[5];
  const float* gbo_w_s2mv   = (const float*)d_in[6];
  const float* gbo_b_mv     = (const float*)d_in[7];
  const float* gbo_w_mvs2s  = (const float*)d_in[8];
  const float* gbo_w_s2s    = (const float*)d_in[9];
  const float* gbo_b_s      = (const float*)d_in[10];
  const float* l1_w_mv      = (const float*)d_in[11];
  const float* l1_w_s2mv    = (const float*)d_in[12];
  const float* l1_b_mv      = (const float*)d_in[13];
  const float* l1_w_mvs2s   = (const float*)d_in[14];
  const float* l1_w_s2s     = (const float*)d_in[15];
  const float* l1_b_s       = (const float*)d_in[16];
  const float* l2_w_mv      = (const float*)d_in[17];
  const float* l2_w_s2mv    = (const float*)d_in[18];
  const float* l2_b_mv      = (const float*)d_in[19];
  const float* l2_w_mvs2s   = (const float*)d_in[20];
  const float* l2_w_s2s     = (const float*)d_in[21];
  const float* l2_b_s       = (const float*)d_in[22];
  float* W   = (float*)d_ws;
  float* out = (float*)d_out;

  prep_pack<<<(W_TOTAL + 255) / 256, 256, 0, stream>>>(
      gb_w_mv, gb_w_s2mv, gbo_w_mv, gbo_w_s2mv, gbo_w_mvs2s, gbo_w_s2s,
      l1_w_mv, l1_w_s2mv, l1_w_mvs2s, l1_w_s2s,
      l2_w_mv, l2_w_s2mv, l2_w_mvs2s, l2_w_s2s, W);

  fused<<<NPTS / PPB, 256, 0, stream>>>(
      xin, sinp, gb_b_mv, gbo_b_mv, gbo_b_s, l1_b_mv, l1_b_s, l2_b_mv, l2_b_s, W, out);
}